// Round 22
// baseline (3555.620 us; speedup 1.0000x reference)
//
#include <hip/hip_runtime.h>
#include <math.h>

#define N_PTS 262144
#define KC 256
#define DIM 64
#define MAX_ITERS 10

// ===========================================================================
// Bit-exact XLA:CPU f32 arithmetic (validated R11-R21 — DO NOT ALTER):
//   x2/c2: rounded squares (fmaf(v,v,0)) + strict sequential f32 add chain
//   dot:   ascending-k FMA chain;  d2 = (x2 + c2) - 2*dot
//   argmin: strict-< first-min, first-NaN override
//   segment_sum: per (k,d), i-ascending sequential plain f32 adds
//   update: f32 sums/counts division (0/0 -> NaN)
// R22: full T14 split. R21 issued+wrote in the same phase (vmcnt in-phase ->
// phase = stage latency ~600-800cyc). Now loads are held IN REGISTERS across
// the barrier: phase c writes data loaded at phase c-1 (latency covered by a
// whole chain phase), issues loads for c+2, prefetches order for c+3.
// vA/vB + srcA/srcB ping-pong, loop unrolled 2x (all indices compile-time).
// ===========================================================================

__device__ __forceinline__ float seq_rowsum_sq64(const float* p)
{
    float s = fmaf(p[0], p[0], 0.f);
    #pragma unroll
    for (int d = 1; d < DIM; ++d) s = s + fmaf(p[d], p[d], 0.f);
    return s;
}

__global__ void detect_idx(const int* __restrict__ a, int* __restrict__ mode)
{
    int zeros = 0;
    for (int j = 1; j < 256; j += 2) zeros += (a[j] == 0);
    *mode = (zeros >= 2) ? 1 : 0;
}

__global__ __launch_bounds__(256) void init_gather(
    const float* __restrict__ data, const void* __restrict__ idxraw,
    const int* __restrict__ mode,
    float* __restrict__ C, int* __restrict__ done)
{
    int t = blockIdx.x * 256 + threadIdx.x;
    if (t < KC * DIM) {
        int k = t >> 6;
        long long src = (*mode) ? ((const long long*)idxraw)[k]
                                : (long long)((const int*)idxraw)[k];
        C[t] = data[(size_t)src * DIM + (t & 63)];
    }
    if (t == 0) *done = 0;
}

__global__ __launch_bounds__(256) void c2_init(
    const float* __restrict__ C, float* __restrict__ c2, int* __restrict__ nanidx)
{
    int k = threadIdx.x;
    float p[DIM];
    #pragma unroll
    for (int d = 0; d < DIM; ++d) p[d] = C[k * DIM + d];
    c2[k] = seq_rowsum_sq64(p);
    __syncthreads();
    if (k == 0) {
        int ni = -1;
        for (int kk = 0; kk < KC; ++kk)
            if (isnan(c2[kk])) { ni = kk; break; }
        *nanidx = ni;
    }
}

// assign: UNCHANGED validated arithmetic.
__global__ __launch_bounds__(256) void assign_k(
    const float* __restrict__ data, const float* __restrict__ C,
    const float* __restrict__ c2, const int* __restrict__ nanidx,
    int* __restrict__ labels, const int* __restrict__ done)
{
    if (*done) return;
    int i = blockIdx.x * 256 + threadIdx.x;
    int ni = *nanidx;
    if (ni >= 0) { labels[i] = ni; return; }

    float p[DIM];
    const float4* r = (const float4*)(data + (size_t)i * DIM);
    #pragma unroll
    for (int j = 0; j < 16; ++j) {
        float4 v = r[j];
        p[4 * j + 0] = v.x; p[4 * j + 1] = v.y;
        p[4 * j + 2] = v.z; p[4 * j + 3] = v.w;
    }
    float xx = seq_rowsum_sq64(p);

    float bestd = INFINITY;
    int best = 0;
    for (int k0 = 0; k0 < KC; k0 += 4) {
        const float* c0 = C + (size_t)k0 * DIM;
        float a0 = 0.f, a1 = 0.f, a2 = 0.f, a3 = 0.f;
        #pragma unroll
        for (int d = 0; d < DIM; ++d) {
            float pd = p[d];
            a0 = fmaf(c0[d], pd, a0);
            a1 = fmaf(c0[DIM + d], pd, a1);
            a2 = fmaf(c0[2 * DIM + d], pd, a2);
            a3 = fmaf(c0[3 * DIM + d], pd, a3);
        }
        float d0 = (xx + c2[k0 + 0]) - 2.f * a0;
        float d1 = (xx + c2[k0 + 1]) - 2.f * a1;
        float d2v = (xx + c2[k0 + 2]) - 2.f * a2;
        float d3 = (xx + c2[k0 + 3]) - 2.f * a3;
        if (d0 < bestd) { bestd = d0; best = k0 + 0; }
        if (d1 < bestd) { bestd = d1; best = k0 + 1; }
        if (d2v < bestd) { bestd = d2v; best = k0 + 2; }
        if (d3 < bestd) { bestd = d3; best = k0 + 3; }
    }
    labels[i] = best;
}

// ---- sort pass A: per-chunk histogram
__global__ __launch_bounds__(256) void hist_k(
    const int* __restrict__ labels, int* __restrict__ hist,
    const int* __restrict__ done)
{
    if (*done) return;
    __shared__ int h[KC];
    int b = blockIdx.x;
    h[threadIdx.x] = 0;
    __syncthreads();
    int base = b * 1024;
    for (int j = threadIdx.x; j < 1024; j += 256)
        atomicAdd(&h[labels[base + j]], 1);
    __syncthreads();
    hist[b * KC + threadIdx.x] = h[threadIdx.x];
}

// ---- sort pass B: column prefix + exclusive scan (integer, order-free)
__global__ __launch_bounds__(256) void prefix_k(
    int* __restrict__ hist, int* __restrict__ seg_start,
    float* __restrict__ counts, const int* __restrict__ done)
{
    if (*done) return;
    int k = threadIdx.x;
    int run = 0;
    #pragma unroll 8
    for (int b = 0; b < 256; ++b) {
        int v = hist[b * KC + k];
        hist[b * KC + k] = run;
        run += v;
    }
    __shared__ int sc[KC];
    sc[k] = run;
    __syncthreads();
    for (int off = 1; off < KC; off <<= 1) {
        int v = (k >= off) ? sc[k - off] : 0;
        __syncthreads();
        sc[k] += v;
        __syncthreads();
    }
    int base = sc[k] - run;
    seg_start[k] = base;
    if (k == 0) seg_start[KC] = N_PTS;
    counts[k] = (float)run;
    #pragma unroll 8
    for (int b = 0; b < 256; ++b)
        hist[b * KC + k] += base;
}

// ---- sort pass C: order-preserving scatter (ascending j per chunk)
__global__ __launch_bounds__(256) void scatter_k(
    const int* __restrict__ labels, const int* __restrict__ hist,
    int* __restrict__ order, const int* __restrict__ done)
{
    if (*done) return;
    __shared__ int lab_s[1024];
    int b = blockIdx.x, k = threadIdx.x;
    int base = b * 1024;
    for (int j = k; j < 1024; j += 256) lab_s[j] = labels[base + j];
    __syncthreads();
    int pos = hist[b * KC + k];
    for (int j = 0; j < 1024; ++j) {
        if (lab_s[j] == k) order[pos++] = base + j;
    }
}

// ---- segment sum, full T14 async pipeline. Block = cluster, 512 threads.
// Wave 0 = chain (LDS only). Waves 1-7: at phase c ds_write data for chunk
// c+1 (loaded during phase c-1 -> vmcnt already satisfied), issue loads for
// chunk c+2, prefetch order for c+3. Register ping-pong vA/vB + srcA/srcB,
// loop unrolled 2x so every array index is compile-time.
// Chain: chunks ascending, j ascending = (label,i) ascending. EXACT.
__global__ __launch_bounds__(512, 2) void sum_pipe2(
    const float* __restrict__ data, const int* __restrict__ order,
    const int* __restrict__ seg_start, float* __restrict__ sums,
    const int* __restrict__ done)
{
    if (*done) return;
    __shared__ float buf[2][128][DIM];      // 64 KB
    int k = blockIdx.x;
    int t = threadIdx.x;
    int beg = seg_start[k], end = seg_start[k + 1];
    int n = end - beg;
    int nchunk = (n + 127) >> 7;
    bool stager = (t >= 64);
    int st = t - 64;                        // 0..447

    int row[5], q[5];
    #pragma unroll
    for (int i = 0; i < 5; ++i) {
        int sl = st + i * 448;
        row[i] = sl >> 4; q[i] = sl & 15;
    }
    int srcA[5], srcB[5];
    float4 vA[5], vB[5];
#define RC(r, m) ((r) < (m) ? (r) : (m) - 1)
    const float4* d4 = (const float4*)data;

    // prologue: stage chunk 0 sync; load srcA(order c1) -> vA(data c1);
    // load srcB(order c2)
    if (stager && nchunk > 0) {
        int m0 = n < 128 ? n : 128;
        int sP[5]; float4 vP[5];
        #pragma unroll
        for (int i = 0; i < 5; ++i) sP[i] = order[beg + RC(row[i], m0)];
        #pragma unroll
        for (int i = 0; i < 5; ++i) vP[i] = d4[(size_t)sP[i] * 16 + q[i]];
        #pragma unroll
        for (int i = 0; i < 5; ++i)
            if (row[i] < m0) ((float4*)&buf[0][0][0])[st + i * 448] = vP[i];
        if (nchunk > 1) {
            int m1 = n - 128; if (m1 > 128) m1 = 128;
            #pragma unroll
            for (int i = 0; i < 5; ++i) srcA[i] = order[beg + 128 + RC(row[i], m1)];
            #pragma unroll
            for (int i = 0; i < 5; ++i) vA[i] = d4[(size_t)srcA[i] * 16 + q[i]];
        }
        if (nchunk > 2) {
            int m2 = n - 256; if (m2 > 128) m2 = 128;
            #pragma unroll
            for (int i = 0; i < 5; ++i) srcB[i] = order[beg + 256 + RC(row[i], m2)];
        }
    }
    __syncthreads();

    float s = 0.f;
    for (int c = 0; c < nchunk; c += 2) {
        // even phase: chain chunk c (buf[0]); write vA->buf[1] (chunk c+1);
        // load vB (chunk c+2 via srcB); prefetch srcA (order c+3)
        if (stager) {
            if (c + 1 < nchunk) {
                int m1 = n - ((c + 1) << 7); if (m1 > 128) m1 = 128;
                #pragma unroll
                for (int i = 0; i < 5; ++i)
                    if (row[i] < m1) ((float4*)&buf[1][0][0])[st + i * 448] = vA[i];
            }
            if (c + 2 < nchunk) {
                #pragma unroll
                for (int i = 0; i < 5; ++i) vB[i] = d4[(size_t)srcB[i] * 16 + q[i]];
            }
            if (c + 3 < nchunk) {
                int b3 = beg + ((c + 3) << 7);
                int m3 = n - ((c + 3) << 7); if (m3 > 128) m3 = 128;
                #pragma unroll
                for (int i = 0; i < 5; ++i) srcA[i] = order[b3 + RC(row[i], m3)];
            }
        } else {
            int m = n - (c << 7); if (m > 128) m = 128;
            #pragma unroll 16
            for (int j = 0; j < m; ++j)
                s = s + buf[0][j][t];
        }
        __syncthreads();
        if (c + 1 >= nchunk) break;
        // odd phase: chain chunk c+1 (buf[1]); write vB->buf[0] (chunk c+2);
        // load vA (chunk c+3 via srcA); prefetch srcB (order c+4)
        if (stager) {
            if (c + 2 < nchunk) {
                int m2 = n - ((c + 2) << 7); if (m2 > 128) m2 = 128;
                #pragma unroll
                for (int i = 0; i < 5; ++i)
                    if (row[i] < m2) ((float4*)&buf[0][0][0])[st + i * 448] = vB[i];
            }
            if (c + 3 < nchunk) {
                #pragma unroll
                for (int i = 0; i < 5; ++i) vA[i] = d4[(size_t)srcA[i] * 16 + q[i]];
            }
            if (c + 4 < nchunk) {
                int b4 = beg + ((c + 4) << 7);
                int m4 = n - ((c + 4) << 7); if (m4 > 128) m4 = 128;
                #pragma unroll
                for (int i = 0; i < 5; ++i) srcB[i] = order[b4 + RC(row[i], m4)];
            }
        } else {
            int m = n - ((c + 1) << 7); if (m > 128) m = 128;
            #pragma unroll 16
            for (int j = 0; j < m; ++j)
                s = s + buf[1][j][t];
        }
        __syncthreads();
    }
#undef RC
    if (t < 64) sums[k * DIM + t] = s;
}

// fallback segment-sum (validated R11) when ws has no room for sort buffers
__global__ __launch_bounds__(64) void accum_scan(
    const float* __restrict__ data, const int* __restrict__ labels,
    float* __restrict__ sums, float* __restrict__ counts,
    const int* __restrict__ done)
{
    if (*done) return;
    int k = blockIdx.x;
    int d = threadIdx.x;
    __shared__ int lab_s[1024];
    float s = 0.f;
    int cnt = 0;
    for (int base = 0; base < N_PTS; base += 1024) {
        for (int j = d; j < 1024; j += 64) lab_s[j] = labels[base + j];
        __syncthreads();
        #pragma unroll 8
        for (int j = 0; j < 1024; ++j) {
            if (lab_s[j] == k) { s = s + data[(size_t)(base + j) * DIM + d]; ++cnt; }
        }
        __syncthreads();
    }
    sums[k * DIM + d] = s;
    if (d == 0) counts[k] = (float)cnt;
}

// ---- update + c2 fused (validated)
__global__ __launch_bounds__(256) void update_c2_k(
    float* __restrict__ C, const float* __restrict__ sums,
    const float* __restrict__ counts, float* __restrict__ c2,
    int* __restrict__ nanidx, int* __restrict__ done)
{
    if (*done) return;
    __shared__ double red[256];
    int k = threadIdx.x;

    float cnt = counts[k];
    float nc[DIM];
    double local = 0.0;
    #pragma unroll
    for (int d = 0; d < DIM; ++d) {
        float v = sums[k * DIM + d] / cnt;
        nc[d] = v;
        float old = C[k * DIM + d];
        double diff = (double)v - (double)old;
        local = fma(diff, diff, local);
        C[k * DIM + d] = v;
    }
    c2[k] = seq_rowsum_sq64(nc);

    red[k] = local;
    __syncthreads();
    if (k == 0) {
        int ni = -1;
        for (int kk = 0; kk < KC; ++kk)
            if (isnan(c2[kk])) { ni = kk; break; }
        *nanidx = ni;
    }
    for (int s = 128; s > 0; s >>= 1) {
        if (k < s) red[k] += red[k + s];
        __syncthreads();
    }
    if (k == 0 && red[0] < 1e-8) *done = 1;    // (1e-4)^2, NaN stays not-done
}

extern "C" void kernel_launch(void* const* d_in, const int* in_sizes, int n_in,
                              void* d_out, int out_size, void* d_ws, size_t ws_size,
                              hipStream_t stream)
{
    const float* data = (const float*)d_in[0];
    const void*  idx  = d_in[1];
    int* labels = (int*)d_out;

    float* C      = (float*)d_ws;               // 16384 f
    float* sums   = C + KC * DIM;               // 16384 f
    float* counts = sums + KC * DIM;            // 256 f
    float* c2     = counts + KC;                // 256 f
    int*   done      = (int*)(c2 + KC);
    int*   mode      = done + 1;
    int*   nanidx    = done + 2;
    int*   seg_start = done + 4;                // 257 ints
    int*   hist      = seg_start + 260;         // 65536 ints
    int*   order     = hist + KC * 256;         // 262144 ints
    size_t need_sort = (size_t)((char*)(order + N_PTS) - (char*)d_ws);
    bool fast = ws_size >= need_sort;           // ~1.4 MB

    detect_idx<<<1, 1, 0, stream>>>((const int*)idx, mode);
    init_gather<<<64, 256, 0, stream>>>(data, idx, mode, C, done);
    c2_init<<<1, 256, 0, stream>>>(C, c2, nanidx);

    for (int it = 0; it < MAX_ITERS; ++it) {
        assign_k<<<N_PTS / 256, 256, 0, stream>>>(data, C, c2, nanidx, labels, done);
        if (fast) {
            hist_k<<<256, 256, 0, stream>>>(labels, hist, done);
            prefix_k<<<1, 256, 0, stream>>>(hist, seg_start, counts, done);
            scatter_k<<<256, 256, 0, stream>>>(labels, hist, order, done);
            sum_pipe2<<<KC, 512, 0, stream>>>(data, order, seg_start, sums, done);
        } else {
            accum_scan<<<KC, 64, 0, stream>>>(data, labels, sums, counts, done);
        }
        update_c2_k<<<1, 256, 0, stream>>>(C, sums, counts, c2, nanidx, done);
    }
}

// Round 23
// 3282.071 us; speedup vs baseline: 1.0833x; 1.0833x over previous
//
#include <hip/hip_runtime.h>
#include <math.h>

#define N_PTS 262144
#define KC 256
#define DIM 64
#define MAX_ITERS 10
#define CHUNK 256

// ===========================================================================
// Bit-exact XLA:CPU f32 arithmetic (validated R11-R22 — DO NOT ALTER):
//   x2/c2: rounded squares (fmaf(v,v,0)) + strict sequential f32 add chain
//   dot:   ascending-k FMA chain;  d2 = (x2 + c2) - 2*dot
//   argmin: strict-< first-min, first-NaN override
//   segment_sum: per (k,d), i-ascending sequential plain f32 adds
//   update: f32 sums/counts division (0/0 -> NaN)
// R23: phase-geometry fix. R22's cross-barrier register hold SPILLED
// (WRITE_SIZE 64KB->16MB scratch). Revert to R21's in-phase staging and
// instead grow CHUNK 128->256 (dbuf 128KB LDS): chain phase ~1536cyc now
// COVERS the ~1000cyc stage latency; barriers halve. ~6.5-7 cyc/elem.
// ===========================================================================

__device__ __forceinline__ float seq_rowsum_sq64(const float* p)
{
    float s = fmaf(p[0], p[0], 0.f);
    #pragma unroll
    for (int d = 1; d < DIM; ++d) s = s + fmaf(p[d], p[d], 0.f);
    return s;
}

__global__ void detect_idx(const int* __restrict__ a, int* __restrict__ mode)
{
    int zeros = 0;
    for (int j = 1; j < 256; j += 2) zeros += (a[j] == 0);
    *mode = (zeros >= 2) ? 1 : 0;
}

__global__ __launch_bounds__(256) void init_gather(
    const float* __restrict__ data, const void* __restrict__ idxraw,
    const int* __restrict__ mode,
    float* __restrict__ C, int* __restrict__ done)
{
    int t = blockIdx.x * 256 + threadIdx.x;
    if (t < KC * DIM) {
        int k = t >> 6;
        long long src = (*mode) ? ((const long long*)idxraw)[k]
                                : (long long)((const int*)idxraw)[k];
        C[t] = data[(size_t)src * DIM + (t & 63)];
    }
    if (t == 0) *done = 0;
}

__global__ __launch_bounds__(256) void c2_init(
    const float* __restrict__ C, float* __restrict__ c2, int* __restrict__ nanidx)
{
    int k = threadIdx.x;
    float p[DIM];
    #pragma unroll
    for (int d = 0; d < DIM; ++d) p[d] = C[k * DIM + d];
    c2[k] = seq_rowsum_sq64(p);
    __syncthreads();
    if (k == 0) {
        int ni = -1;
        for (int kk = 0; kk < KC; ++kk)
            if (isnan(c2[kk])) { ni = kk; break; }
        *nanidx = ni;
    }
}

// assign: UNCHANGED validated arithmetic.
__global__ __launch_bounds__(256) void assign_k(
    const float* __restrict__ data, const float* __restrict__ C,
    const float* __restrict__ c2, const int* __restrict__ nanidx,
    int* __restrict__ labels, const int* __restrict__ done)
{
    if (*done) return;
    int i = blockIdx.x * 256 + threadIdx.x;
    int ni = *nanidx;
    if (ni >= 0) { labels[i] = ni; return; }

    float p[DIM];
    const float4* r = (const float4*)(data + (size_t)i * DIM);
    #pragma unroll
    for (int j = 0; j < 16; ++j) {
        float4 v = r[j];
        p[4 * j + 0] = v.x; p[4 * j + 1] = v.y;
        p[4 * j + 2] = v.z; p[4 * j + 3] = v.w;
    }
    float xx = seq_rowsum_sq64(p);

    float bestd = INFINITY;
    int best = 0;
    for (int k0 = 0; k0 < KC; k0 += 4) {
        const float* c0 = C + (size_t)k0 * DIM;
        float a0 = 0.f, a1 = 0.f, a2 = 0.f, a3 = 0.f;
        #pragma unroll
        for (int d = 0; d < DIM; ++d) {
            float pd = p[d];
            a0 = fmaf(c0[d], pd, a0);
            a1 = fmaf(c0[DIM + d], pd, a1);
            a2 = fmaf(c0[2 * DIM + d], pd, a2);
            a3 = fmaf(c0[3 * DIM + d], pd, a3);
        }
        float d0 = (xx + c2[k0 + 0]) - 2.f * a0;
        float d1 = (xx + c2[k0 + 1]) - 2.f * a1;
        float d2v = (xx + c2[k0 + 2]) - 2.f * a2;
        float d3 = (xx + c2[k0 + 3]) - 2.f * a3;
        if (d0 < bestd) { bestd = d0; best = k0 + 0; }
        if (d1 < bestd) { bestd = d1; best = k0 + 1; }
        if (d2v < bestd) { bestd = d2v; best = k0 + 2; }
        if (d3 < bestd) { bestd = d3; best = k0 + 3; }
    }
    labels[i] = best;
}

// ---- sort pass A: per-chunk histogram
__global__ __launch_bounds__(256) void hist_k(
    const int* __restrict__ labels, int* __restrict__ hist,
    const int* __restrict__ done)
{
    if (*done) return;
    __shared__ int h[KC];
    int b = blockIdx.x;
    h[threadIdx.x] = 0;
    __syncthreads();
    int base = b * 1024;
    for (int j = threadIdx.x; j < 1024; j += 256)
        atomicAdd(&h[labels[base + j]], 1);
    __syncthreads();
    hist[b * KC + threadIdx.x] = h[threadIdx.x];
}

// ---- sort pass B: column prefix + exclusive scan (integer, order-free)
__global__ __launch_bounds__(256) void prefix_k(
    int* __restrict__ hist, int* __restrict__ seg_start,
    float* __restrict__ counts, const int* __restrict__ done)
{
    if (*done) return;
    int k = threadIdx.x;
    int run = 0;
    #pragma unroll 8
    for (int b = 0; b < 256; ++b) {
        int v = hist[b * KC + k];
        hist[b * KC + k] = run;
        run += v;
    }
    __shared__ int sc[KC];
    sc[k] = run;
    __syncthreads();
    for (int off = 1; off < KC; off <<= 1) {
        int v = (k >= off) ? sc[k - off] : 0;
        __syncthreads();
        sc[k] += v;
        __syncthreads();
    }
    int base = sc[k] - run;
    seg_start[k] = base;
    if (k == 0) seg_start[KC] = N_PTS;
    counts[k] = (float)run;
    #pragma unroll 8
    for (int b = 0; b < 256; ++b)
        hist[b * KC + k] += base;
}

// ---- sort pass C: order-preserving scatter (ascending j per chunk)
__global__ __launch_bounds__(256) void scatter_k(
    const int* __restrict__ labels, const int* __restrict__ hist,
    int* __restrict__ order, const int* __restrict__ done)
{
    if (*done) return;
    __shared__ int lab_s[1024];
    int b = blockIdx.x, k = threadIdx.x;
    int base = b * 1024;
    for (int j = k; j < 1024; j += 256) lab_s[j] = labels[base + j];
    __syncthreads();
    int pos = hist[b * KC + k];
    for (int j = 0; j < 1024; ++j) {
        if (lab_s[j] == k) order[pos++] = base + j;
    }
}

// ---- segment sum, CHUNK=256 double-buffered pipeline (128 KB LDS).
// Block = cluster, 512 threads. Wave 0 chains chunk c from LDS (256 adds
// ~1536cyc). Waves 1-7 (448 thr x 10 slots): order for chunk c+1 was
// prefetched during phase c-1 -> data loads issue at phase start, vmcnt +
// ds_write in-phase (~1000cyc, hidden under the chain), then prefetch order
// for c+2. NOTHING held across barriers (R22 spill lesson).
// Chain: chunks ascending, j ascending = (label,i) ascending. EXACT.
__global__ __launch_bounds__(512, 1) void sum_pipe3(
    const float* __restrict__ data, const int* __restrict__ order,
    const int* __restrict__ seg_start, float* __restrict__ sums,
    const int* __restrict__ done)
{
    if (*done) return;
    __shared__ float buf[2][CHUNK][DIM];    // 128 KB
    int k = blockIdx.x;
    int t = threadIdx.x;
    int beg = seg_start[k], end = seg_start[k + 1];
    int n = end - beg;
    int nchunk = (n + CHUNK - 1) / CHUNK;
    bool stager = (t >= 64);
    int st = t - 64;                        // 0..447

    int row[10], q[10], ordA[10];
    #pragma unroll
    for (int i = 0; i < 10; ++i) {
        int sl = st + i * 448;              // 0..4479; used slots < m*16
        row[i] = sl >> 4; q[i] = sl & 15;
    }
#define RC(r, m) ((r) < (m) ? (r) : (m) - 1)
    const float4* d4 = (const float4*)data;

    // prologue: stage chunk 0 synchronously; prefetch order for chunk 1
    if (stager && nchunk > 0) {
        int m0 = n < CHUNK ? n : CHUNK;
        int s0[10];
        #pragma unroll
        for (int i = 0; i < 10; ++i) s0[i] = order[beg + RC(row[i], m0)];
        float4 v[10];
        #pragma unroll
        for (int i = 0; i < 10; ++i) v[i] = d4[(size_t)s0[i] * 16 + q[i]];
        #pragma unroll
        for (int i = 0; i < 10; ++i)
            if (row[i] < m0) ((float4*)&buf[0][0][0])[st + i * 448] = v[i];
        if (nchunk > 1) {
            int m1 = n - CHUNK; if (m1 > CHUNK) m1 = CHUNK;
            #pragma unroll
            for (int i = 0; i < 10; ++i) ordA[i] = order[beg + CHUNK + RC(row[i], m1)];
        }
    }
    __syncthreads();

    float s = 0.f;
    for (int c = 0; c < nchunk; ++c) {
        if (stager) {
            if (c + 1 < nchunk) {
                int m1 = n - (c + 1) * CHUNK; if (m1 > CHUNK) m1 = CHUNK;
                float4 v[10];
                #pragma unroll
                for (int i = 0; i < 10; ++i) v[i] = d4[(size_t)ordA[i] * 16 + q[i]];
                int nxt = (c + 1) & 1;
                #pragma unroll
                for (int i = 0; i < 10; ++i)
                    if (row[i] < m1) ((float4*)&buf[nxt][0][0])[st + i * 448] = v[i];
                if (c + 2 < nchunk) {       // prefetch order for c+2
                    int b2 = beg + (c + 2) * CHUNK;
                    int m2 = n - (c + 2) * CHUNK; if (m2 > CHUNK) m2 = CHUNK;
                    #pragma unroll
                    for (int i = 0; i < 10; ++i) ordA[i] = order[b2 + RC(row[i], m2)];
                }
            }
        } else {
            int m = n - c * CHUNK; if (m > CHUNK) m = CHUNK;
            int cur = c & 1;
            #pragma unroll 16
            for (int j = 0; j < m; ++j)
                s = s + buf[cur][j][t];     // sequential chain, lane = dim
        }
        __syncthreads();
    }
#undef RC
    if (t < 64) sums[k * DIM + t] = s;
}

// fallback segment-sum (validated R11) when ws has no room for sort buffers
__global__ __launch_bounds__(64) void accum_scan(
    const float* __restrict__ data, const int* __restrict__ labels,
    float* __restrict__ sums, float* __restrict__ counts,
    const int* __restrict__ done)
{
    if (*done) return;
    int k = blockIdx.x;
    int d = threadIdx.x;
    __shared__ int lab_s[1024];
    float s = 0.f;
    int cnt = 0;
    for (int base = 0; base < N_PTS; base += 1024) {
        for (int j = d; j < 1024; j += 64) lab_s[j] = labels[base + j];
        __syncthreads();
        #pragma unroll 8
        for (int j = 0; j < 1024; ++j) {
            if (lab_s[j] == k) { s = s + data[(size_t)(base + j) * DIM + d]; ++cnt; }
        }
        __syncthreads();
    }
    sums[k * DIM + d] = s;
    if (d == 0) counts[k] = (float)cnt;
}

// ---- update + c2 fused (validated)
__global__ __launch_bounds__(256) void update_c2_k(
    float* __restrict__ C, const float* __restrict__ sums,
    const float* __restrict__ counts, float* __restrict__ c2,
    int* __restrict__ nanidx, int* __restrict__ done)
{
    if (*done) return;
    __shared__ double red[256];
    int k = threadIdx.x;

    float cnt = counts[k];
    float nc[DIM];
    double local = 0.0;
    #pragma unroll
    for (int d = 0; d < DIM; ++d) {
        float v = sums[k * DIM + d] / cnt;
        nc[d] = v;
        float old = C[k * DIM + d];
        double diff = (double)v - (double)old;
        local = fma(diff, diff, local);
        C[k * DIM + d] = v;
    }
    c2[k] = seq_rowsum_sq64(nc);

    red[k] = local;
    __syncthreads();
    if (k == 0) {
        int ni = -1;
        for (int kk = 0; kk < KC; ++kk)
            if (isnan(c2[kk])) { ni = kk; break; }
        *nanidx = ni;
    }
    for (int s = 128; s > 0; s >>= 1) {
        if (k < s) red[k] += red[k + s];
        __syncthreads();
    }
    if (k == 0 && red[0] < 1e-8) *done = 1;    // (1e-4)^2, NaN stays not-done
}

extern "C" void kernel_launch(void* const* d_in, const int* in_sizes, int n_in,
                              void* d_out, int out_size, void* d_ws, size_t ws_size,
                              hipStream_t stream)
{
    const float* data = (const float*)d_in[0];
    const void*  idx  = d_in[1];
    int* labels = (int*)d_out;

    float* C      = (float*)d_ws;               // 16384 f
    float* sums   = C + KC * DIM;               // 16384 f
    float* counts = sums + KC * DIM;            // 256 f
    float* c2     = counts + KC;                // 256 f
    int*   done      = (int*)(c2 + KC);
    int*   mode      = done + 1;
    int*   nanidx    = done + 2;
    int*   seg_start = done + 4;                // 257 ints
    int*   hist      = seg_start + 260;         // 65536 ints
    int*   order     = hist + KC * 256;         // 262144 ints
    size_t need_sort = (size_t)((char*)(order + N_PTS) - (char*)d_ws);
    bool fast = ws_size >= need_sort;           // ~1.4 MB

    detect_idx<<<1, 1, 0, stream>>>((const int*)idx, mode);
    init_gather<<<64, 256, 0, stream>>>(data, idx, mode, C, done);
    c2_init<<<1, 256, 0, stream>>>(C, c2, nanidx);

    for (int it = 0; it < MAX_ITERS; ++it) {
        assign_k<<<N_PTS / 256, 256, 0, stream>>>(data, C, c2, nanidx, labels, done);
        if (fast) {
            hist_k<<<256, 256, 0, stream>>>(labels, hist, done);
            prefix_k<<<1, 256, 0, stream>>>(hist, seg_start, counts, done);
            scatter_k<<<256, 256, 0, stream>>>(labels, hist, order, done);
            sum_pipe3<<<KC, 512, 0, stream>>>(data, order, seg_start, sums, done);
        } else {
            accum_scan<<<KC, 64, 0, stream>>>(data, labels, sums, counts, done);
        }
        update_c2_k<<<1, 256, 0, stream>>>(C, sums, counts, c2, nanidx, done);
    }
}

// Round 24
// 3099.499 us; speedup vs baseline: 1.1472x; 1.0589x over previous
//
#include <hip/hip_runtime.h>
#include <math.h>

#define N_PTS 262144
#define KC 256
#define DIM 64
#define MAX_ITERS 10
#define CHUNK 256

// ===========================================================================
// Bit-exact XLA:CPU f32 arithmetic (validated R11-R23 — DO NOT ALTER):
//   x2/c2: rounded squares (fmaf(v,v,0)) + strict sequential f32 add chain
//   dot:   ascending-k FMA chain;  d2 = (x2 + c2) - 2*dot
//   argmin: strict-< first-min, first-NaN override
//   segment_sum: per (k,d), i-ascending sequential plain f32 adds
//   update: f32 sums/counts division (0/0 -> NaN)
// R24: transposed+swizzled LDS so the chain consumes 4 elems per ds_read_b128
// (granule g of dim d stored at address g^(d&7): quarter-wave = 32 banks,
// 2-way = free). Stagers gather 4 points x one dim-quad, transpose in
// registers, write 4 swizzled b128. Chain adds stay j-ascending. Only ordA
// ints cross barriers (R22 float4-hold spill lesson).
// ===========================================================================

__device__ __forceinline__ float seq_rowsum_sq64(const float* p)
{
    float s = fmaf(p[0], p[0], 0.f);
    #pragma unroll
    for (int d = 1; d < DIM; ++d) s = s + fmaf(p[d], p[d], 0.f);
    return s;
}

__global__ void detect_idx(const int* __restrict__ a, int* __restrict__ mode)
{
    int zeros = 0;
    for (int j = 1; j < 256; j += 2) zeros += (a[j] == 0);
    *mode = (zeros >= 2) ? 1 : 0;
}

__global__ __launch_bounds__(256) void init_gather(
    const float* __restrict__ data, const void* __restrict__ idxraw,
    const int* __restrict__ mode,
    float* __restrict__ C, int* __restrict__ done)
{
    int t = blockIdx.x * 256 + threadIdx.x;
    if (t < KC * DIM) {
        int k = t >> 6;
        long long src = (*mode) ? ((const long long*)idxraw)[k]
                                : (long long)((const int*)idxraw)[k];
        C[t] = data[(size_t)src * DIM + (t & 63)];
    }
    if (t == 0) *done = 0;
}

__global__ __launch_bounds__(256) void c2_init(
    const float* __restrict__ C, float* __restrict__ c2, int* __restrict__ nanidx)
{
    int k = threadIdx.x;
    float p[DIM];
    #pragma unroll
    for (int d = 0; d < DIM; ++d) p[d] = C[k * DIM + d];
    c2[k] = seq_rowsum_sq64(p);
    __syncthreads();
    if (k == 0) {
        int ni = -1;
        for (int kk = 0; kk < KC; ++kk)
            if (isnan(c2[kk])) { ni = kk; break; }
        *nanidx = ni;
    }
}

// assign: UNCHANGED validated arithmetic.
__global__ __launch_bounds__(256) void assign_k(
    const float* __restrict__ data, const float* __restrict__ C,
    const float* __restrict__ c2, const int* __restrict__ nanidx,
    int* __restrict__ labels, const int* __restrict__ done)
{
    if (*done) return;
    int i = blockIdx.x * 256 + threadIdx.x;
    int ni = *nanidx;
    if (ni >= 0) { labels[i] = ni; return; }

    float p[DIM];
    const float4* r = (const float4*)(data + (size_t)i * DIM);
    #pragma unroll
    for (int j = 0; j < 16; ++j) {
        float4 v = r[j];
        p[4 * j + 0] = v.x; p[4 * j + 1] = v.y;
        p[4 * j + 2] = v.z; p[4 * j + 3] = v.w;
    }
    float xx = seq_rowsum_sq64(p);

    float bestd = INFINITY;
    int best = 0;
    for (int k0 = 0; k0 < KC; k0 += 4) {
        const float* c0 = C + (size_t)k0 * DIM;
        float a0 = 0.f, a1 = 0.f, a2 = 0.f, a3 = 0.f;
        #pragma unroll
        for (int d = 0; d < DIM; ++d) {
            float pd = p[d];
            a0 = fmaf(c0[d], pd, a0);
            a1 = fmaf(c0[DIM + d], pd, a1);
            a2 = fmaf(c0[2 * DIM + d], pd, a2);
            a3 = fmaf(c0[3 * DIM + d], pd, a3);
        }
        float d0 = (xx + c2[k0 + 0]) - 2.f * a0;
        float d1 = (xx + c2[k0 + 1]) - 2.f * a1;
        float d2v = (xx + c2[k0 + 2]) - 2.f * a2;
        float d3 = (xx + c2[k0 + 3]) - 2.f * a3;
        if (d0 < bestd) { bestd = d0; best = k0 + 0; }
        if (d1 < bestd) { bestd = d1; best = k0 + 1; }
        if (d2v < bestd) { bestd = d2v; best = k0 + 2; }
        if (d3 < bestd) { bestd = d3; best = k0 + 3; }
    }
    labels[i] = best;
}

// ---- sort pass A: per-chunk histogram
__global__ __launch_bounds__(256) void hist_k(
    const int* __restrict__ labels, int* __restrict__ hist,
    const int* __restrict__ done)
{
    if (*done) return;
    __shared__ int h[KC];
    int b = blockIdx.x;
    h[threadIdx.x] = 0;
    __syncthreads();
    int base = b * 1024;
    for (int j = threadIdx.x; j < 1024; j += 256)
        atomicAdd(&h[labels[base + j]], 1);
    __syncthreads();
    hist[b * KC + threadIdx.x] = h[threadIdx.x];
}

// ---- sort pass B: column prefix + exclusive scan (integer, order-free)
__global__ __launch_bounds__(256) void prefix_k(
    int* __restrict__ hist, int* __restrict__ seg_start,
    float* __restrict__ counts, const int* __restrict__ done)
{
    if (*done) return;
    int k = threadIdx.x;
    int run = 0;
    #pragma unroll 8
    for (int b = 0; b < 256; ++b) {
        int v = hist[b * KC + k];
        hist[b * KC + k] = run;
        run += v;
    }
    __shared__ int sc[KC];
    sc[k] = run;
    __syncthreads();
    for (int off = 1; off < KC; off <<= 1) {
        int v = (k >= off) ? sc[k - off] : 0;
        __syncthreads();
        sc[k] += v;
        __syncthreads();
    }
    int base = sc[k] - run;
    seg_start[k] = base;
    if (k == 0) seg_start[KC] = N_PTS;
    counts[k] = (float)run;
    #pragma unroll 8
    for (int b = 0; b < 256; ++b)
        hist[b * KC + k] += base;
}

// ---- sort pass C: order-preserving scatter (ascending j per chunk)
__global__ __launch_bounds__(256) void scatter_k(
    const int* __restrict__ labels, const int* __restrict__ hist,
    int* __restrict__ order, const int* __restrict__ done)
{
    if (*done) return;
    __shared__ int lab_s[1024];
    int b = blockIdx.x, k = threadIdx.x;
    int base = b * 1024;
    for (int j = k; j < 1024; j += 256) lab_s[j] = labels[base + j];
    __syncthreads();
    int pos = hist[b * KC + k];
    for (int j = 0; j < 1024; ++j) {
        if (lab_s[j] == k) order[pos++] = base + j;
    }
}

// ---- segment sum, transposed+swizzled LDS pipeline. Block = cluster, 512
// threads, CHUNK=256 dbuf (128 KB). Stager group = (granule g, dim-quad q):
// gather 4 point-float4s, 4x4 transpose, 4 ds_write_b128 at addr g^(d&7).
// Chain lane d: per granule one ds_read_b128 at g^(d&7), adds x,y,z,w =
// j=4g..4g+3 -> strict j-ascending chain. EXACT.
__global__ __launch_bounds__(512, 1) void sum_pipe4(
    const float* __restrict__ data, const int* __restrict__ order,
    const int* __restrict__ seg_start, float* __restrict__ sums,
    const int* __restrict__ done)
{
    if (*done) return;
    __shared__ float buf[2][DIM][CHUNK];    // 128 KB
    int k = blockIdx.x;
    int t = threadIdx.x;
    int beg = seg_start[k], end = seg_start[k + 1];
    int n = end - beg;
    int nchunk = (n + CHUNK - 1) / CHUNK;
    bool stager = (t >= 64);
    int st = t - 64;                        // 0..447

    // 3 groups per stager: G = st + i*448 (1344 >= 1024 groups/chunk)
    int gg[3], qq[3];
    #pragma unroll
    for (int i = 0; i < 3; ++i) {
        int G = st + i * 448;
        gg[i] = G >> 4;                     // granule 0..83 (valid < 64)
        qq[i] = G & 15;                     // dim quad
    }
    int ordA[12];
    const float4* d4 = (const float4*)data;

#define ORDX(cc)                                                              \
    {                                                                         \
        int _b = beg + (cc) * CHUNK;                                          \
        int _m = n - (cc) * CHUNK; if (_m > CHUNK) _m = CHUNK;                \
        _Pragma("unroll")                                                     \
        for (int i = 0; i < 3; ++i) {                                         \
            _Pragma("unroll")                                                 \
            for (int r = 0; r < 4; ++r) {                                     \
                int _rr = 4 * gg[i] + r; if (_rr >= _m) _rr = _m - 1;         \
                ordA[i * 4 + r] = order[_b + _rr];                            \
            }                                                                 \
        }                                                                     \
    }
#define STAGEX(cc, which)                                                     \
    {                                                                         \
        int _m = n - (cc) * CHUNK; if (_m > CHUNK) _m = CHUNK;                \
        int _ng = (_m + 3) >> 2;                                              \
        float4* _bp = (float4*)&buf[which][0][0];                             \
        _Pragma("unroll")                                                     \
        for (int i = 0; i < 3; ++i) {                                         \
            if (gg[i] < _ng) {                                                \
                float4 a0 = d4[(size_t)ordA[i * 4 + 0] * 16 + qq[i]];         \
                float4 a1 = d4[(size_t)ordA[i * 4 + 1] * 16 + qq[i]];         \
                float4 a2 = d4[(size_t)ordA[i * 4 + 2] * 16 + qq[i]];         \
                float4 a3 = d4[(size_t)ordA[i * 4 + 3] * 16 + qq[i]];         \
                int _d0 = qq[i] * 4;                                          \
                _bp[(_d0 + 0) * (CHUNK / 4) + (gg[i] ^ ((_d0 + 0) & 7))] =    \
                    make_float4(a0.x, a1.x, a2.x, a3.x);                      \
                _bp[(_d0 + 1) * (CHUNK / 4) + (gg[i] ^ ((_d0 + 1) & 7))] =    \
                    make_float4(a0.y, a1.y, a2.y, a3.y);                      \
                _bp[(_d0 + 2) * (CHUNK / 4) + (gg[i] ^ ((_d0 + 2) & 7))] =    \
                    make_float4(a0.z, a1.z, a2.z, a3.z);                      \
                _bp[(_d0 + 3) * (CHUNK / 4) + (gg[i] ^ ((_d0 + 3) & 7))] =    \
                    make_float4(a0.w, a1.w, a2.w, a3.w);                      \
            }                                                                 \
        }                                                                     \
    }

    // prologue: order+stage chunk 0 synchronously; prefetch order for chunk 1
    if (stager && nchunk > 0) {
        ORDX(0);
        STAGEX(0, 0);
        if (nchunk > 1) ORDX(1);
    }
    __syncthreads();

    float s = 0.f;
    int x7 = t & 7;
    for (int c = 0; c < nchunk; ++c) {
        if (stager) {
            if (c + 1 < nchunk) STAGEX(c + 1, (c + 1) & 1);
            if (c + 2 < nchunk) ORDX(c + 2);
        } else {
            int m = n - c * CHUNK; if (m > CHUNK) m = CHUNK;
            int mg = m >> 2;
            int cur = c & 1;
            const float4* rp = (const float4*)&buf[cur][t][0];
            #pragma unroll 8
            for (int g = 0; g < mg; ++g) {
                float4 v = rp[g ^ x7];
                s = s + v.x; s = s + v.y; s = s + v.z; s = s + v.w;
            }
            for (int j = mg * 4; j < m; ++j)
                s = s + buf[cur][t][(((j >> 2) ^ x7) << 2) + (j & 3)];
        }
        __syncthreads();
    }
#undef ORDX
#undef STAGEX
    if (t < 64) sums[k * DIM + t] = s;
}

// fallback segment-sum (validated R11) when ws has no room for sort buffers
__global__ __launch_bounds__(64) void accum_scan(
    const float* __restrict__ data, const int* __restrict__ labels,
    float* __restrict__ sums, float* __restrict__ counts,
    const int* __restrict__ done)
{
    if (*done) return;
    int k = blockIdx.x;
    int d = threadIdx.x;
    __shared__ int lab_s[1024];
    float s = 0.f;
    int cnt = 0;
    for (int base = 0; base < N_PTS; base += 1024) {
        for (int j = d; j < 1024; j += 64) lab_s[j] = labels[base + j];
        __syncthreads();
        #pragma unroll 8
        for (int j = 0; j < 1024; ++j) {
            if (lab_s[j] == k) { s = s + data[(size_t)(base + j) * DIM + d]; ++cnt; }
        }
        __syncthreads();
    }
    sums[k * DIM + d] = s;
    if (d == 0) counts[k] = (float)cnt;
}

// ---- update + c2 fused (validated)
__global__ __launch_bounds__(256) void update_c2_k(
    float* __restrict__ C, const float* __restrict__ sums,
    const float* __restrict__ counts, float* __restrict__ c2,
    int* __restrict__ nanidx, int* __restrict__ done)
{
    if (*done) return;
    __shared__ double red[256];
    int k = threadIdx.x;

    float cnt = counts[k];
    float nc[DIM];
    double local = 0.0;
    #pragma unroll
    for (int d = 0; d < DIM; ++d) {
        float v = sums[k * DIM + d] / cnt;
        nc[d] = v;
        float old = C[k * DIM + d];
        double diff = (double)v - (double)old;
        local = fma(diff, diff, local);
        C[k * DIM + d] = v;
    }
    c2[k] = seq_rowsum_sq64(nc);

    red[k] = local;
    __syncthreads();
    if (k == 0) {
        int ni = -1;
        for (int kk = 0; kk < KC; ++kk)
            if (isnan(c2[kk])) { ni = kk; break; }
        *nanidx = ni;
    }
    for (int s = 128; s > 0; s >>= 1) {
        if (k < s) red[k] += red[k + s];
        __syncthreads();
    }
    if (k == 0 && red[0] < 1e-8) *done = 1;    // (1e-4)^2, NaN stays not-done
}

extern "C" void kernel_launch(void* const* d_in, const int* in_sizes, int n_in,
                              void* d_out, int out_size, void* d_ws, size_t ws_size,
                              hipStream_t stream)
{
    const float* data = (const float*)d_in[0];
    const void*  idx  = d_in[1];
    int* labels = (int*)d_out;

    float* C      = (float*)d_ws;               // 16384 f
    float* sums   = C + KC * DIM;               // 16384 f
    float* counts = sums + KC * DIM;            // 256 f
    float* c2     = counts + KC;                // 256 f
    int*   done      = (int*)(c2 + KC);
    int*   mode      = done + 1;
    int*   nanidx    = done + 2;
    int*   seg_start = done + 4;                // 257 ints
    int*   hist      = seg_start + 260;         // 65536 ints
    int*   order     = hist + KC * 256;         // 262144 ints
    size_t need_sort = (size_t)((char*)(order + N_PTS) - (char*)d_ws);
    bool fast = ws_size >= need_sort;           // ~1.4 MB

    detect_idx<<<1, 1, 0, stream>>>((const int*)idx, mode);
    init_gather<<<64, 256, 0, stream>>>(data, idx, mode, C, done);
    c2_init<<<1, 256, 0, stream>>>(C, c2, nanidx);

    for (int it = 0; it < MAX_ITERS; ++it) {
        assign_k<<<N_PTS / 256, 256, 0, stream>>>(data, C, c2, nanidx, labels, done);
        if (fast) {
            hist_k<<<256, 256, 0, stream>>>(labels, hist, done);
            prefix_k<<<1, 256, 0, stream>>>(hist, seg_start, counts, done);
            scatter_k<<<256, 256, 0, stream>>>(labels, hist, order, done);
            sum_pipe4<<<KC, 512, 0, stream>>>(data, order, seg_start, sums, done);
        } else {
            accum_scan<<<KC, 64, 0, stream>>>(data, labels, sums, counts, done);
        }
        update_c2_k<<<1, 256, 0, stream>>>(C, sums, counts, c2, nanidx, done);
    }
}

// Round 25
// 3093.869 us; speedup vs baseline: 1.1492x; 1.0018x over previous
//
#include <hip/hip_runtime.h>
#include <math.h>

#define N_PTS 262144
#define KC 256
#define DIM 64
#define MAX_ITERS 10
#define CHUNK 256

// ===========================================================================
// Bit-exact XLA:CPU f32 arithmetic (validated R11-R24 — DO NOT ALTER):
//   x2/c2: rounded squares (fmaf(v,v,0)) + strict sequential f32 add chain
//   dot:   ascending-k FMA chain;  d2 = (x2 + c2) - 2*dot
//   argmin: strict-< first-min, first-NaN override
//   segment_sum: per (k,d), i-ascending sequential plain f32 adds
//   update: f32 sums/counts division (0/0 -> NaN)
// R25: assign_k register residency. R24 profile: assign VGPR=40 -> p[64]
// spilled-by-reload (re-fetch point row per k-group, 2.4x VALU/VMEM issue).
// __launch_bounds__(256,2) caps 256 VGPR -> p resident; k0+=8 (8 chains)
// halves group overhead. Chains still ascending-d; compares ascending-k ->
// first-min semantics identical.
// ===========================================================================

__device__ __forceinline__ float seq_rowsum_sq64(const float* p)
{
    float s = fmaf(p[0], p[0], 0.f);
    #pragma unroll
    for (int d = 1; d < DIM; ++d) s = s + fmaf(p[d], p[d], 0.f);
    return s;
}

__global__ void detect_idx(const int* __restrict__ a, int* __restrict__ mode)
{
    int zeros = 0;
    for (int j = 1; j < 256; j += 2) zeros += (a[j] == 0);
    *mode = (zeros >= 2) ? 1 : 0;
}

__global__ __launch_bounds__(256) void init_gather(
    const float* __restrict__ data, const void* __restrict__ idxraw,
    const int* __restrict__ mode,
    float* __restrict__ C, int* __restrict__ done)
{
    int t = blockIdx.x * 256 + threadIdx.x;
    if (t < KC * DIM) {
        int k = t >> 6;
        long long src = (*mode) ? ((const long long*)idxraw)[k]
                                : (long long)((const int*)idxraw)[k];
        C[t] = data[(size_t)src * DIM + (t & 63)];
    }
    if (t == 0) *done = 0;
}

__global__ __launch_bounds__(256) void c2_init(
    const float* __restrict__ C, float* __restrict__ c2, int* __restrict__ nanidx)
{
    int k = threadIdx.x;
    float p[DIM];
    #pragma unroll
    for (int d = 0; d < DIM; ++d) p[d] = C[k * DIM + d];
    c2[k] = seq_rowsum_sq64(p);
    __syncthreads();
    if (k == 0) {
        int ni = -1;
        for (int kk = 0; kk < KC; ++kk)
            if (isnan(c2[kk])) { ni = kk; break; }
        *nanidx = ni;
    }
}

// assign: validated arithmetic; 8 chains + register-resident point row.
__global__ __launch_bounds__(256, 2) void assign_k(
    const float* __restrict__ data, const float* __restrict__ C,
    const float* __restrict__ c2, const int* __restrict__ nanidx,
    int* __restrict__ labels, const int* __restrict__ done)
{
    if (*done) return;
    int i = blockIdx.x * 256 + threadIdx.x;
    int ni = *nanidx;
    if (ni >= 0) { labels[i] = ni; return; }

    float p[DIM];
    const float4* r = (const float4*)(data + (size_t)i * DIM);
    #pragma unroll
    for (int j = 0; j < 16; ++j) {
        float4 v = r[j];
        p[4 * j + 0] = v.x; p[4 * j + 1] = v.y;
        p[4 * j + 2] = v.z; p[4 * j + 3] = v.w;
    }
    float xx = seq_rowsum_sq64(p);

    float bestd = INFINITY;
    int best = 0;
    for (int k0 = 0; k0 < KC; k0 += 8) {
        const float* c0 = C + (size_t)k0 * DIM;
        float a0 = 0.f, a1 = 0.f, a2 = 0.f, a3 = 0.f;
        float a4 = 0.f, a5 = 0.f, a6 = 0.f, a7 = 0.f;
        #pragma unroll
        for (int d = 0; d < DIM; ++d) {
            float pd = p[d];
            a0 = fmaf(c0[d],           pd, a0);
            a1 = fmaf(c0[DIM + d],     pd, a1);
            a2 = fmaf(c0[2 * DIM + d], pd, a2);
            a3 = fmaf(c0[3 * DIM + d], pd, a3);
            a4 = fmaf(c0[4 * DIM + d], pd, a4);
            a5 = fmaf(c0[5 * DIM + d], pd, a5);
            a6 = fmaf(c0[6 * DIM + d], pd, a6);
            a7 = fmaf(c0[7 * DIM + d], pd, a7);
        }
        float d0 = (xx + c2[k0 + 0]) - 2.f * a0;
        float d1 = (xx + c2[k0 + 1]) - 2.f * a1;
        float d2v = (xx + c2[k0 + 2]) - 2.f * a2;
        float d3 = (xx + c2[k0 + 3]) - 2.f * a3;
        float d4 = (xx + c2[k0 + 4]) - 2.f * a4;
        float d5 = (xx + c2[k0 + 5]) - 2.f * a5;
        float d6 = (xx + c2[k0 + 6]) - 2.f * a6;
        float d7 = (xx + c2[k0 + 7]) - 2.f * a7;
        if (d0 < bestd) { bestd = d0; best = k0 + 0; }
        if (d1 < bestd) { bestd = d1; best = k0 + 1; }
        if (d2v < bestd) { bestd = d2v; best = k0 + 2; }
        if (d3 < bestd) { bestd = d3; best = k0 + 3; }
        if (d4 < bestd) { bestd = d4; best = k0 + 4; }
        if (d5 < bestd) { bestd = d5; best = k0 + 5; }
        if (d6 < bestd) { bestd = d6; best = k0 + 6; }
        if (d7 < bestd) { bestd = d7; best = k0 + 7; }
    }
    labels[i] = best;
}

// ---- sort pass A: per-chunk histogram
__global__ __launch_bounds__(256) void hist_k(
    const int* __restrict__ labels, int* __restrict__ hist,
    const int* __restrict__ done)
{
    if (*done) return;
    __shared__ int h[KC];
    int b = blockIdx.x;
    h[threadIdx.x] = 0;
    __syncthreads();
    int base = b * 1024;
    for (int j = threadIdx.x; j < 1024; j += 256)
        atomicAdd(&h[labels[base + j]], 1);
    __syncthreads();
    hist[b * KC + threadIdx.x] = h[threadIdx.x];
}

// ---- sort pass B: column prefix + exclusive scan (integer, order-free)
__global__ __launch_bounds__(256) void prefix_k(
    int* __restrict__ hist, int* __restrict__ seg_start,
    float* __restrict__ counts, const int* __restrict__ done)
{
    if (*done) return;
    int k = threadIdx.x;
    int run = 0;
    #pragma unroll 8
    for (int b = 0; b < 256; ++b) {
        int v = hist[b * KC + k];
        hist[b * KC + k] = run;
        run += v;
    }
    __shared__ int sc[KC];
    sc[k] = run;
    __syncthreads();
    for (int off = 1; off < KC; off <<= 1) {
        int v = (k >= off) ? sc[k - off] : 0;
        __syncthreads();
        sc[k] += v;
        __syncthreads();
    }
    int base = sc[k] - run;
    seg_start[k] = base;
    if (k == 0) seg_start[KC] = N_PTS;
    counts[k] = (float)run;
    #pragma unroll 8
    for (int b = 0; b < 256; ++b)
        hist[b * KC + k] += base;
}

// ---- sort pass C: order-preserving scatter (ascending j per chunk)
__global__ __launch_bounds__(256) void scatter_k(
    const int* __restrict__ labels, const int* __restrict__ hist,
    int* __restrict__ order, const int* __restrict__ done)
{
    if (*done) return;
    __shared__ int lab_s[1024];
    int b = blockIdx.x, k = threadIdx.x;
    int base = b * 1024;
    for (int j = k; j < 1024; j += 256) lab_s[j] = labels[base + j];
    __syncthreads();
    int pos = hist[b * KC + k];
    for (int j = 0; j < 1024; ++j) {
        if (lab_s[j] == k) order[pos++] = base + j;
    }
}

// ---- segment sum, transposed+swizzled LDS pipeline (R24 validated).
__global__ __launch_bounds__(512, 1) void sum_pipe4(
    const float* __restrict__ data, const int* __restrict__ order,
    const int* __restrict__ seg_start, float* __restrict__ sums,
    const int* __restrict__ done)
{
    if (*done) return;
    __shared__ float buf[2][DIM][CHUNK];    // 128 KB
    int k = blockIdx.x;
    int t = threadIdx.x;
    int beg = seg_start[k], end = seg_start[k + 1];
    int n = end - beg;
    int nchunk = (n + CHUNK - 1) / CHUNK;
    bool stager = (t >= 64);
    int st = t - 64;                        // 0..447

    int gg[3], qq[3];
    #pragma unroll
    for (int i = 0; i < 3; ++i) {
        int G = st + i * 448;
        gg[i] = G >> 4;
        qq[i] = G & 15;
    }
    int ordA[12];
    const float4* d4 = (const float4*)data;

#define ORDX(cc)                                                              \
    {                                                                         \
        int _b = beg + (cc) * CHUNK;                                          \
        int _m = n - (cc) * CHUNK; if (_m > CHUNK) _m = CHUNK;                \
        _Pragma("unroll")                                                     \
        for (int i = 0; i < 3; ++i) {                                         \
            _Pragma("unroll")                                                 \
            for (int r = 0; r < 4; ++r) {                                     \
                int _rr = 4 * gg[i] + r; if (_rr >= _m) _rr = _m - 1;         \
                ordA[i * 4 + r] = order[_b + _rr];                            \
            }                                                                 \
        }                                                                     \
    }
#define STAGEX(cc, which)                                                     \
    {                                                                         \
        int _m = n - (cc) * CHUNK; if (_m > CHUNK) _m = CHUNK;                \
        int _ng = (_m + 3) >> 2;                                              \
        float4* _bp = (float4*)&buf[which][0][0];                             \
        _Pragma("unroll")                                                     \
        for (int i = 0; i < 3; ++i) {                                         \
            if (gg[i] < _ng) {                                                \
                float4 a0 = d4[(size_t)ordA[i * 4 + 0] * 16 + qq[i]];         \
                float4 a1 = d4[(size_t)ordA[i * 4 + 1] * 16 + qq[i]];         \
                float4 a2 = d4[(size_t)ordA[i * 4 + 2] * 16 + qq[i]];         \
                float4 a3 = d4[(size_t)ordA[i * 4 + 3] * 16 + qq[i]];         \
                int _d0 = qq[i] * 4;                                          \
                _bp[(_d0 + 0) * (CHUNK / 4) + (gg[i] ^ ((_d0 + 0) & 7))] =    \
                    make_float4(a0.x, a1.x, a2.x, a3.x);                      \
                _bp[(_d0 + 1) * (CHUNK / 4) + (gg[i] ^ ((_d0 + 1) & 7))] =    \
                    make_float4(a0.y, a1.y, a2.y, a3.y);                      \
                _bp[(_d0 + 2) * (CHUNK / 4) + (gg[i] ^ ((_d0 + 2) & 7))] =    \
                    make_float4(a0.z, a1.z, a2.z, a3.z);                      \
                _bp[(_d0 + 3) * (CHUNK / 4) + (gg[i] ^ ((_d0 + 3) & 7))] =    \
                    make_float4(a0.w, a1.w, a2.w, a3.w);                      \
            }                                                                 \
        }                                                                     \
    }

    if (stager && nchunk > 0) {
        ORDX(0);
        STAGEX(0, 0);
        if (nchunk > 1) ORDX(1);
    }
    __syncthreads();

    float s = 0.f;
    int x7 = t & 7;
    for (int c = 0; c < nchunk; ++c) {
        if (stager) {
            if (c + 1 < nchunk) STAGEX(c + 1, (c + 1) & 1);
            if (c + 2 < nchunk) ORDX(c + 2);
        } else {
            int m = n - c * CHUNK; if (m > CHUNK) m = CHUNK;
            int mg = m >> 2;
            int cur = c & 1;
            const float4* rp = (const float4*)&buf[cur][t][0];
            #pragma unroll 8
            for (int g = 0; g < mg; ++g) {
                float4 v = rp[g ^ x7];
                s = s + v.x; s = s + v.y; s = s + v.z; s = s + v.w;
            }
            for (int j = mg * 4; j < m; ++j)
                s = s + buf[cur][t][(((j >> 2) ^ x7) << 2) + (j & 3)];
        }
        __syncthreads();
    }
#undef ORDX
#undef STAGEX
    if (t < 64) sums[k * DIM + t] = s;
}

// fallback segment-sum (validated R11) when ws has no room for sort buffers
__global__ __launch_bounds__(64) void accum_scan(
    const float* __restrict__ data, const int* __restrict__ labels,
    float* __restrict__ sums, float* __restrict__ counts,
    const int* __restrict__ done)
{
    if (*done) return;
    int k = blockIdx.x;
    int d = threadIdx.x;
    __shared__ int lab_s[1024];
    float s = 0.f;
    int cnt = 0;
    for (int base = 0; base < N_PTS; base += 1024) {
        for (int j = d; j < 1024; j += 64) lab_s[j] = labels[base + j];
        __syncthreads();
        #pragma unroll 8
        for (int j = 0; j < 1024; ++j) {
            if (lab_s[j] == k) { s = s + data[(size_t)(base + j) * DIM + d]; ++cnt; }
        }
        __syncthreads();
    }
    sums[k * DIM + d] = s;
    if (d == 0) counts[k] = (float)cnt;
}

// ---- update + c2 fused (validated)
__global__ __launch_bounds__(256) void update_c2_k(
    float* __restrict__ C, const float* __restrict__ sums,
    const float* __restrict__ counts, float* __restrict__ c2,
    int* __restrict__ nanidx, int* __restrict__ done)
{
    if (*done) return;
    __shared__ double red[256];
    int k = threadIdx.x;

    float cnt = counts[k];
    float nc[DIM];
    double local = 0.0;
    #pragma unroll
    for (int d = 0; d < DIM; ++d) {
        float v = sums[k * DIM + d] / cnt;
        nc[d] = v;
        float old = C[k * DIM + d];
        double diff = (double)v - (double)old;
        local = fma(diff, diff, local);
        C[k * DIM + d] = v;
    }
    c2[k] = seq_rowsum_sq64(nc);

    red[k] = local;
    __syncthreads();
    if (k == 0) {
        int ni = -1;
        for (int kk = 0; kk < KC; ++kk)
            if (isnan(c2[kk])) { ni = kk; break; }
        *nanidx = ni;
    }
    for (int s = 128; s > 0; s >>= 1) {
        if (k < s) red[k] += red[k + s];
        __syncthreads();
    }
    if (k == 0 && red[0] < 1e-8) *done = 1;    // (1e-4)^2, NaN stays not-done
}

extern "C" void kernel_launch(void* const* d_in, const int* in_sizes, int n_in,
                              void* d_out, int out_size, void* d_ws, size_t ws_size,
                              hipStream_t stream)
{
    const float* data = (const float*)d_in[0];
    const void*  idx  = d_in[1];
    int* labels = (int*)d_out;

    float* C      = (float*)d_ws;               // 16384 f
    float* sums   = C + KC * DIM;               // 16384 f
    float* counts = sums + KC * DIM;            // 256 f
    float* c2     = counts + KC;                // 256 f
    int*   done      = (int*)(c2 + KC);
    int*   mode      = done + 1;
    int*   nanidx    = done + 2;
    int*   seg_start = done + 4;                // 257 ints
    int*   hist      = seg_start + 260;         // 65536 ints
    int*   order     = hist + KC * 256;         // 262144 ints
    size_t need_sort = (size_t)((char*)(order + N_PTS) - (char*)d_ws);
    bool fast = ws_size >= need_sort;           // ~1.4 MB

    detect_idx<<<1, 1, 0, stream>>>((const int*)idx, mode);
    init_gather<<<64, 256, 0, stream>>>(data, idx, mode, C, done);
    c2_init<<<1, 256, 0, stream>>>(C, c2, nanidx);

    for (int it = 0; it < MAX_ITERS; ++it) {
        assign_k<<<N_PTS / 256, 256, 0, stream>>>(data, C, c2, nanidx, labels, done);
        if (fast) {
            hist_k<<<256, 256, 0, stream>>>(labels, hist, done);
            prefix_k<<<1, 256, 0, stream>>>(hist, seg_start, counts, done);
            scatter_k<<<256, 256, 0, stream>>>(labels, hist, order, done);
            sum_pipe4<<<KC, 512, 0, stream>>>(data, order, seg_start, sums, done);
        } else {
            accum_scan<<<KC, 64, 0, stream>>>(data, labels, sums, counts, done);
        }
        update_c2_k<<<1, 256, 0, stream>>>(C, sums, counts, c2, nanidx, done);
    }
}